// Round 6
// baseline (583.311 us; speedup 1.0000x reference)
//
#include <hip/hip_runtime.h>

#define NN     2048
#define DIM    512
#define NH     8
#define HD     64
#define NE     32768
#define EPAD   32832
#define CHUNKS 8
#define CHSZ   (NN/CHUNKS)      /* 256 keys per chunk */
#define NJT    (CHSZ/64)        /* 4 key-tiles of 64 per chunk */
#define QBLK   32
#define LOG2E  1.4426950408889634f

typedef __attribute__((ext_vector_type(8))) short bf16x8;
typedef __attribute__((ext_vector_type(4))) float f32x4;
typedef __attribute__((ext_vector_type(4))) unsigned int u32x4;

#define MFMA(a,b,c) __builtin_amdgcn_mfma_f32_16x16x32_bf16((a),(b),(c),0,0,0)

__device__ __forceinline__ float bf2f(unsigned int u16){
  union { unsigned int i; float f; } v; v.i = u16 << 16; return v.f;
}
__device__ __forceinline__ unsigned short f2bf(float f){
  union { float ff; unsigned int i; } v; v.ff = f;
  return (unsigned short)((v.i + 0x7fffu + ((v.i >> 16) & 1u)) >> 16);
}

// ---------------- fused prep: cvt (blocks 0..1539) + weight transpose (blocks 1540..2563) ----------------
__global__ __launch_bounds__(256) void prep_k(
    const float* __restrict__ X, const float* __restrict__ ef, const float* __restrict__ ew,
    unsigned short* __restrict__ Xb, unsigned short* __restrict__ pEF, unsigned short* __restrict__ pEW,
    const float* __restrict__ a0, const float* __restrict__ a1,
    const float* __restrict__ a2, const float* __restrict__ a3,
    unsigned short* __restrict__ Wt)
{
  __shared__ unsigned short tile[32][33];
  if (blockIdx.x < 1540){
    long g = (long)blockIdx.x*256 + threadIdx.x;   // 8-element group index
    const long GX = (long)NN*DIM/8;                // 131072 groups
    const long GE = (long)EPAD*8;                  // 262656 groups
    const float* src; unsigned short* dst; long off, lim8;
    if (g < GX){ src = X;  dst = Xb;  off = g;        lim8 = GX; }
    else if (g < GX+GE){ src = ef; dst = pEF; off = g-GX; lim8 = (long)NE*8; }
    else { off = g-GX-GE; if (off >= 512) return; src = ew; dst = pEW; lim8 = 320; }
    unsigned short o[8];
    if (off < lim8){
      #pragma unroll
      for (int i=0;i<8;i++) o[i] = f2bf(src[off*8+i]);
    } else {
      #pragma unroll
      for (int i=0;i<8;i++) o[i] = 0;
    }
    *(uint4*)(dst + off*8) = *(const uint4*)o;
  } else {
    int b2 = blockIdx.x - 1540;                    // 0..1023
    int bz = b2 >> 8, rem = b2 & 255;
    int bx = (rem & 15)*32, by = (rem >> 4)*32;
    int tx = threadIdx.x & 31, ty = threadIdx.x >> 5;
    const float* src = bz==0 ? a0 : bz==1 ? a1 : bz==2 ? a2 : a3;
    unsigned short* dst = Wt + (size_t)bz*DIM*DIM;
    #pragma unroll
    for (int i=0;i<32;i+=8) tile[ty+i][tx] = f2bf(src[(size_t)(by+ty+i)*DIM + bx+tx]);
    __syncthreads();
    #pragma unroll
    for (int i=0;i<32;i+=8) dst[(size_t)(bx+ty+i)*DIM + by+tx] = tile[tx][ty+i];
  }
}

// ---------------- generic C[M][N] = A1[M][K] * A2[N][K]^T + bias (final O-proj) ----------------
__global__ __launch_bounds__(256) void gemm_bt(
    const unsigned short* __restrict__ A1, const unsigned short* __restrict__ A2,
    const float* __restrict__ bias, unsigned short* __restrict__ C, float* __restrict__ Cf,
    int M, int N, int K, int bias_row)
{
  int lane = threadIdx.x & 63, w = threadIdx.x >> 6;
  int quad = lane >> 4, low = lane & 15;
  int m0 = blockIdx.y*64 + w*16;
  int n0 = blockIdx.x*32;
  f32x4 acc[2];
  acc[0] = (f32x4){0.f,0.f,0.f,0.f};
  acc[1] = (f32x4){0.f,0.f,0.f,0.f};
  #pragma unroll 4
  for (int k0=0; k0<K; k0+=32){
    bf16x8 a = *(const bf16x8*)(A1 + (size_t)(m0+low)*K + k0 + quad*8);
    #pragma unroll
    for (int t=0;t<2;t++){
      bf16x8 b = *(const bf16x8*)(A2 + (size_t)(n0+16*t+low)*K + k0 + quad*8);
      acc[t] = MFMA(a, b, acc[t]);
    }
  }
  #pragma unroll
  for (int t=0;t<2;t++){
    #pragma unroll
    for (int r=0;r<4;r++){
      int row = m0 + quad*4 + r;
      int col = n0 + 16*t + low;
      float v = acc[t][r];
      if (bias) v += bias[bias_row ? row : col];
      if (Cf) Cf[(size_t)row*N + col] = v;
      else    C [(size_t)row*N + col] = f2bf(v);
    }
  }
}

// ---------------- T2 gemm: T2L[l][e][h] = pEF[e]·pEW[l*8+h], per-l 16B rows ----------------
// Layout [8][EPAD][8] bf16: each l's gather window is 525KB -> hot set (l<5) 2.6MB, L2-resident.
__global__ __launch_bounds__(256) void gemm_t2(
    const unsigned short* __restrict__ A1, const unsigned short* __restrict__ A2,
    unsigned short* __restrict__ T2L)
{
  int lane = threadIdx.x & 63, w = threadIdx.x >> 6;
  int quad = lane >> 4, low = lane & 15;
  int m0 = blockIdx.y*64 + w*16;
  int n0 = blockIdx.x*32;
  f32x4 acc[2];
  acc[0] = (f32x4){0.f,0.f,0.f,0.f};
  acc[1] = (f32x4){0.f,0.f,0.f,0.f};
  #pragma unroll
  for (int k0=0; k0<64; k0+=32){
    bf16x8 a = *(const bf16x8*)(A1 + (size_t)(m0+low)*64 + k0 + quad*8);
    #pragma unroll
    for (int t=0;t<2;t++){
      bf16x8 b = *(const bf16x8*)(A2 + (size_t)(n0+16*t+low)*64 + k0 + quad*8);
      acc[t] = MFMA(a, b, acc[t]);
    }
  }
  #pragma unroll
  for (int t=0;t<2;t++){
    #pragma unroll
    for (int r=0;r<4;r++){
      int row = m0 + quad*4 + r;            // edge index
      int col = n0 + 16*t + low;            // l*8+h
      T2L[((size_t)(col>>3)*EPAD + row)*8 + (col&7)] = f2bf(acc[t][r]);
    }
  }
}

// ---------------- co-scheduled bias-gather + fused QKV GEMM ----------------
// blocks 0..511: QKV (MFMA-bound, launched first so they start immediately);
// blocks 512..16895: bias gather (L2-request-bound). Disjoint pipes -> overlap.
__global__ __launch_bounds__(256) void biasqkv_k(
    const unsigned short* __restrict__ T2L, const float* __restrict__ spb,
    const int* __restrict__ dist, const int* __restrict__ sp, const int* __restrict__ maskp,
    unsigned short* __restrict__ biasB,
    const unsigned short* __restrict__ Xb, const unsigned short* __restrict__ Wt,
    const float* __restrict__ bQ, const float* __restrict__ bK, const float* __restrict__ bV,
    unsigned short* __restrict__ Qb, unsigned short* __restrict__ Kb, unsigned short* __restrict__ Vtb)
{
  __shared__ float sptab[48];
  if (blockIdx.x >= 512){
    // ---------- bias gather ----------
    if (threadIdx.x < 48) sptab[threadIdx.x] = spb[threadIdx.x];
    __syncthreads();
    long pix = (long)(blockIdx.x - 512)*256 + threadIdx.x;   // n*NN + m, covers NN*NN
    int dd = __builtin_nontemporal_load(dist + pix);
    int mk = __builtin_nontemporal_load(maskp + pix);
    int e[5];
    #pragma unroll
    for (int l=0;l<5;l++) e[l] = __builtin_nontemporal_load(sp + pix*5 + l);
    dd = dd < 0 ? 0 : (dd > 5 ? 5 : dd);
    float b[8];
    #pragma unroll
    for (int x=0;x<8;x++) b[x] = sptab[dd*8 + x];
    #pragma unroll
    for (int l=0;l<5;l++){
      int ee = e[l];
      if ((unsigned)ee > (unsigned)NE) ee = NE;
      // nt = evict-first: the gather window (525KB/l) has zero L1 reuse; don't thrash L1.
      u32x4 tv = __builtin_nontemporal_load((const u32x4*)(T2L + ((size_t)l*EPAD + ee)*8));
      b[0] += bf2f(tv[0] & 0xffffu); b[1] += bf2f(tv[0] >> 16);
      b[2] += bf2f(tv[1] & 0xffffu); b[3] += bf2f(tv[1] >> 16);
      b[4] += bf2f(tv[2] & 0xffffu); b[5] += bf2f(tv[2] >> 16);
      b[6] += bf2f(tv[3] & 0xffffu); b[7] += bf2f(tv[3] >> 16);
    }
    unsigned short o[8];
    #pragma unroll
    for (int x=0;x<8;x++) o[x] = mk ? f2bf(-1e30f) : f2bf(b[x]);
    *(uint4*)(biasB + pix*8) = *(const uint4*)o;
  } else {
    // ---------- fused Q/K/V GEMM: A-fragment loaded once feeds 3 weights ----------
    int bid = blockIdx.x;                  // 0..511 -> (bx 0..15, by 0..31)
    int lane = threadIdx.x & 63, w = threadIdx.x >> 6;
    int quad = lane >> 4, low = lane & 15;
    int m0 = (bid >> 4)*64 + w*16;         // node row
    int n0 = (bid & 15)*32;                // output col
    f32x4 acc[3][2];
    #pragma unroll
    for (int z=0;z<3;z++){ acc[z][0]=(f32x4){0.f,0.f,0.f,0.f}; acc[z][1]=(f32x4){0.f,0.f,0.f,0.f}; }
    #pragma unroll 2
    for (int k0=0; k0<DIM; k0+=32){
      bf16x8 a = *(const bf16x8*)(Xb + (size_t)(m0+low)*DIM + k0 + quad*8);
      #pragma unroll
      for (int z=0;z<3;z++){
        #pragma unroll
        for (int t=0;t<2;t++){
          bf16x8 b = *(const bf16x8*)(Wt + (size_t)z*DIM*DIM + (size_t)(n0+16*t+low)*DIM + k0 + quad*8);
          acc[z][t] = MFMA(a, b, acc[z][t]);
        }
      }
    }
    #pragma unroll
    for (int t=0;t<2;t++){
      #pragma unroll
      for (int r=0;r<4;r++){
        int row = m0 + quad*4 + r;
        int col = n0 + 16*t + low;
        Qb[(size_t)row*DIM + col] = f2bf(acc[0][t][r] + bQ[col]);
        Kb[(size_t)row*DIM + col] = f2bf(acc[1][t][r] + bK[col]);
        Vtb[(size_t)col*NN + row] = f2bf(acc[2][t][r] + bV[col]);
      }
    }
  }
}

// ---------------- fused attention (3-barrier schedule) ----------------
// block = 512 threads = 8 waves, wave h owns head h; QBLK=32 queries/block.
// Softmax over HEADS per (q,m) pair (reference uses axis=-1 on (n,m,h)!).
// Phase B: S=QK^T -> LDS (pure write; barrier hidden under MFMA issue).
// Phase C: bias added from register-prefetched pb + softmax; P written bf16-packed
//          (2 heads/u32) into planes 0..3 of the SAME LDS block (own-slot rewrite, race-free).
// Phase D: PV reads P as 2x uint4 per fragment (no f32->bf16 conversion chain).
__global__ __launch_bounds__(512, 4) void attn_k(
    const unsigned short* __restrict__ Qb, const unsigned short* __restrict__ Kb,
    const unsigned short* __restrict__ Vt, const unsigned short* __restrict__ biasB,
    float* __restrict__ partO)
{
  __shared__ __attribute__((aligned(16))) float sld[NH][QBLK][68];  // 69.6 KB -> 2 blocks/CU
  unsigned int* p2 = (unsigned int*)sld;   // packed-P view: p2[pair*2176 + row*68 + col]
  int tid = threadIdx.x;
  int lane = tid & 63, h = tid >> 6;
  int quad = lane >> 4, low = lane & 15;
  int q0 = blockIdx.x * QBLK;
  int chunk = blockIdx.y;

  bf16x8 aq[2][2];
  #pragma unroll
  for (int sq=0;sq<2;sq++)
    #pragma unroll
    for (int s=0;s<2;s++)
      aq[sq][s] = *(const bf16x8*)(Qb + (size_t)(q0+sq*16+low)*DIM + h*HD + s*32 + quad*8);

  f32x4 accO[2][4];
  #pragma unroll
  for (int sq=0;sq<2;sq++)
    #pragma unroll
    for (int t=0;t<4;t++) accO[sq][t] = (f32x4){0.f,0.f,0.f,0.f};

  // prefetch first key-tile's bias (coalesced: consecutive tid -> consecutive 16B)
  uint4 pb[4];
  #pragma unroll
  for (int it=0; it<4; ++it){
    int p = tid + it*512;
    int qq = p >> 6, mm = p & 63;
    pb[it] = *(const uint4*)(biasB + ((size_t)(q0+qq)*NN + chunk*CHSZ + mm)*8);
  }

  for (int jt=0; jt<NJT; ++jt){
    int m0 = chunk*CHSZ + jt*64;

    // ---- phase B compute: S = Q K^T (registers only) ----
    f32x4 S[2][4];
    #pragma unroll
    for (int sq=0;sq<2;sq++)
      #pragma unroll
      for (int t=0;t<4;t++) S[sq][t] = (f32x4){0.f,0.f,0.f,0.f};
    #pragma unroll
    for (int s=0;s<2;s++){
      #pragma unroll
      for (int t=0;t<4;t++){
        bf16x8 bk = *(const bf16x8*)(Kb + (size_t)(m0+16*t+low)*DIM + h*HD + s*32 + quad*8);
        #pragma unroll
        for (int sq=0;sq<2;sq++)
          S[sq][t] = MFMA(aq[sq][s], bk, S[sq][t]);
      }
    }
    __syncthreads();   // prev iteration's phase-D readers done (wait hides under MFMA)

    // ---- phase B write: raw scores -> LDS (pure write, no bias rmw) ----
    #pragma unroll
    for (int sq=0;sq<2;sq++){
      #pragma unroll
      for (int t=0;t<4;t++){
        #pragma unroll
        for (int r=0;r<4;r++)
          sld[h][sq*16+quad*4+r][low+16*t] = S[sq][t][r]*0.125f;
      }
    }
    __syncthreads();

    // ---- phase C: bias add (from pb regs) + softmax over heads + packed-P write ----
    #pragma unroll
    for (int it=0; it<4; ++it){
      int p = tid + it*512;
      int qq = p >> 6, mm = p & 63;
      uint4 tv = pb[it];
      float s0[8];
      s0[0] = sld[0][qq][mm] + bf2f(tv.x & 0xffffu);
      s0[1] = sld[1][qq][mm] + bf2f(tv.x >> 16);
      s0[2] = sld[2][qq][mm] + bf2f(tv.y & 0xffffu);
      s0[3] = sld[3][qq][mm] + bf2f(tv.y >> 16);
      s0[4] = sld[4][qq][mm] + bf2f(tv.z & 0xffffu);
      s0[5] = sld[5][qq][mm] + bf2f(tv.z >> 16);
      s0[6] = sld[6][qq][mm] + bf2f(tv.w & 0xffffu);
      s0[7] = sld[7][qq][mm] + bf2f(tv.w >> 16);
      float mx = s0[0];
      #pragma unroll
      for (int x=1;x<8;x++) mx = fmaxf(mx, s0[x]);
      float sum = 0.f;
      #pragma unroll
      for (int x=0;x<8;x++){ s0[x] = exp2f((s0[x]-mx)*LOG2E); sum += s0[x]; }
      float inv = (mx < -1e29f) ? 0.f : 1.f/sum;   // fully-masked pair -> zero weights
      #pragma unroll
      for (int pr=0;pr<4;pr++){
        unsigned int u = (unsigned int)f2bf(s0[2*pr]*inv)
                       | ((unsigned int)f2bf(s0[2*pr+1]*inv) << 16);
        p2[pr*2176 + qq*68 + mm] = u;    // own (qq,mm) slot: no cross-thread hazard
      }
    }
    // issue next tile's bias loads (in flight across D + next B)
    if (jt+1 < NJT){
      #pragma unroll
      for (int it=0; it<4; ++it){
        int p = tid + it*512;
        int qq = p >> 6, mm = p & 63;
        pb[it] = *(const uint4*)(biasB + ((size_t)(q0+qq)*NN + m0 + 64 + mm)*8);
      }
    }
    __syncthreads();

    // ---- phase D (wave h): O += P V ----
    bf16x8 ap[2][2];
    #pragma unroll
    for (int sq=0;sq<2;sq++){
      #pragma unroll
      for (int s=0;s<2;s++){
        const uint4* pp = (const uint4*)(p2 + (h>>1)*2176 + (size_t)(sq*16+low)*68 + s*32 + quad*8);
        uint4 w0 = pp[0], w1 = pp[1];
        bf16x8 a;
        if (h & 1){
          a[0]=(short)(w0.x>>16); a[1]=(short)(w0.y>>16); a[2]=(short)(w0.z>>16); a[3]=(short)(w0.w>>16);
          a[4]=(short)(w1.x>>16); a[5]=(short)(w1.y>>16); a[6]=(short)(w1.z>>16); a[7]=(short)(w1.w>>16);
        } else {
          a[0]=(short)(w0.x&0xffffu); a[1]=(short)(w0.y&0xffffu); a[2]=(short)(w0.z&0xffffu); a[3]=(short)(w0.w&0xffffu);
          a[4]=(short)(w1.x&0xffffu); a[5]=(short)(w1.y&0xffffu); a[6]=(short)(w1.z&0xffffu); a[7]=(short)(w1.w&0xffffu);
        }
        ap[sq][s] = a;
      }
    }
    #pragma unroll
    for (int s=0;s<2;s++){
      #pragma unroll
      for (int t=0;t<4;t++){
        bf16x8 bv = *(const bf16x8*)(Vt + (size_t)(h*HD + 16*t + low)*NN + m0 + s*32 + quad*8);
        #pragma unroll
        for (int sq=0;sq<2;sq++)
          accO[sq][t] = MFMA(ap[sq][s], bv, accO[sq][t]);
      }
    }
  }

  // ---- epilogue: per-chunk partial O (plain sum over m; no softmax state) ----
  #pragma unroll
  for (int sq=0;sq<2;sq++){
    #pragma unroll
    for (int t=0;t<4;t++){
      #pragma unroll
      for (int r=0;r<4;r++){
        int q = sq*16 + quad*4 + r;
        partO[(((size_t)chunk*NN + q0 + q)*NH + h)*HD + 16*t + low] = accO[sq][t][r];
      }
    }
  }
}

// ---------------- sum the CHUNKS partial O's, emit bf16 ----------------
__global__ __launch_bounds__(512) void merge_k(const float* __restrict__ partO,
                                               unsigned short* __restrict__ Obf)
{
  size_t idx = (size_t)blockIdx.x*512 + threadIdx.x;   // q*512 + h*64 + d
  float s = 0.f;
  #pragma unroll
  for (int c=0;c<CHUNKS;c++) s += partO[(size_t)c*NN*DIM + idx];
  Obf[idx] = f2bf(s);
}

extern "C" void kernel_launch(void* const* d_in, const int* in_sizes, int n_in,
                              void* d_out, int out_size, void* d_ws, size_t ws_size,
                              hipStream_t stream)
{
  const float* X    = (const float*)d_in[0];
  const int*  dist  = (const int*)d_in[3];
  const int*  sp    = (const int*)d_in[4];
  const float* ef   = (const float*)d_in[5];
  const int*  maskp = (const int*)d_in[6];
  const float* WQ   = (const float*)d_in[7];
  const float* bQ   = (const float*)d_in[8];
  const float* WK   = (const float*)d_in[9];
  const float* bK   = (const float*)d_in[10];
  const float* WV   = (const float*)d_in[11];
  const float* bV   = (const float*)d_in[12];
  const float* WO   = (const float*)d_in[13];
  const float* bO   = (const float*)d_in[14];
  const float* spb  = (const float*)d_in[15];
  const float* ew   = (const float*)d_in[16];

  char* ws = (char*)d_ws;
  unsigned short* Wt   = (unsigned short*)(ws + 0);            // 4 x 512x512 bf16 (Q,K,V,O transposed)
  unsigned short* Xb   = (unsigned short*)(ws + 2097152);      // 2048x512 bf16 node_feat
  unsigned short* Qb   = (unsigned short*)(ws + 4194304);      // 2048x512 bf16
  unsigned short* Kb   = (unsigned short*)(ws + 6291456);      // 2048x512 bf16
  unsigned short* Vtb  = (unsigned short*)(ws + 8388608);      // 512x2048 bf16 (transposed V)
  unsigned short* pEF  = (unsigned short*)(ws + 10485760);     // EPAD x 64 bf16
  unsigned short* pEW  = (unsigned short*)(ws + 14688256);     // 64 x 64 bf16
  unsigned short* T2L  = (unsigned short*)(ws + 14696448);     // [8][EPAD][8] bf16 per-l rows (4.2MB)
  unsigned short* Obf  = (unsigned short*)(ws + 18898944);     // 2048x512 bf16
  unsigned short* biasB= (unsigned short*)(ws + 20996096);     // NN x NN x 8 bf16 (67 MB)
  float*          pO   = (float*)(ws + 88104960);              // CHUNKS x 2048x512 f32 (33.5 MB; ws ~122 MB)

  prep_k<<<dim3(2564), dim3(256), 0, stream>>>(X, ef, ew, Xb, pEF, pEW, WQ, WK, WV, WO, Wt);
  gemm_t2<<<dim3(2,513), dim3(256), 0, stream>>>(pEF, pEW, T2L);
  biasqkv_k<<<dim3(512 + NN*NN/256), dim3(256), 0, stream>>>(
      T2L, spb, dist, sp, maskp, biasB, Xb, Wt, bQ, bK, bV, Qb, Kb, Vtb);
  attn_k<<<dim3(NN/QBLK, CHUNKS), dim3(512), 0, stream>>>(Qb, Kb, Vtb, biasB, pO);
  merge_k<<<dim3(2048), dim3(512), 0, stream>>>(pO, Obf);
  gemm_bt<<<dim3(16,32), dim3(256), 0, stream>>>(Obf, Wt + 786432, bO, (unsigned short*)nullptr, (float*)d_out, NN, DIM, DIM, 0);
}

// Round 7
// 362.889 us; speedup vs baseline: 1.6074x; 1.6074x over previous
//
#include <hip/hip_runtime.h>

#define NN     2048
#define DIM    512
#define NH     8
#define HD     64
#define NE     32768
#define EPAD   32832
#define CHUNKS 8
#define CHSZ   (NN/CHUNKS)      /* 256 keys per chunk */
#define NJT    (CHSZ/64)        /* 4 key-tiles of 64 per chunk */
#define QBLK   32
#define LOG2E  1.4426950408889634f

typedef __attribute__((ext_vector_type(8))) short bf16x8;
typedef __attribute__((ext_vector_type(4))) float f32x4;
typedef __attribute__((ext_vector_type(4))) unsigned int u32x4;

#define MFMA(a,b,c) __builtin_amdgcn_mfma_f32_16x16x32_bf16((a),(b),(c),0,0,0)

__device__ __forceinline__ float bf2f(unsigned int u16){
  union { unsigned int i; float f; } v; v.i = u16 << 16; return v.f;
}
__device__ __forceinline__ unsigned short f2bf(float f){
  union { float ff; unsigned int i; } v; v.ff = f;
  return (unsigned short)((v.i + 0x7fffu + ((v.i >> 16) & 1u)) >> 16);
}

// ---------------- fused prep: cvt (blocks 0..1539) + weight transpose (blocks 1540..2563) ----------------
__global__ __launch_bounds__(256) void prep_k(
    const float* __restrict__ X, const float* __restrict__ ef, const float* __restrict__ ew,
    unsigned short* __restrict__ Xb, unsigned short* __restrict__ pEF, unsigned short* __restrict__ pEW,
    const float* __restrict__ a0, const float* __restrict__ a1,
    const float* __restrict__ a2, const float* __restrict__ a3,
    unsigned short* __restrict__ Wt)
{
  __shared__ unsigned short tile[32][33];
  if (blockIdx.x < 1540){
    long g = (long)blockIdx.x*256 + threadIdx.x;   // 8-element group index
    const long GX = (long)NN*DIM/8;                // 131072 groups
    const long GE = (long)EPAD*8;                  // 262656 groups
    const float* src; unsigned short* dst; long off, lim8;
    if (g < GX){ src = X;  dst = Xb;  off = g;        lim8 = GX; }
    else if (g < GX+GE){ src = ef; dst = pEF; off = g-GX; lim8 = (long)NE*8; }
    else { off = g-GX-GE; if (off >= 512) return; src = ew; dst = pEW; lim8 = 320; }
    unsigned short o[8];
    if (off < lim8){
      #pragma unroll
      for (int i=0;i<8;i++) o[i] = f2bf(src[off*8+i]);
    } else {
      #pragma unroll
      for (int i=0;i<8;i++) o[i] = 0;
    }
    *(uint4*)(dst + off*8) = *(const uint4*)o;
  } else {
    int b2 = blockIdx.x - 1540;                    // 0..1023
    int bz = b2 >> 8, rem = b2 & 255;
    int bx = (rem & 15)*32, by = (rem >> 4)*32;
    int tx = threadIdx.x & 31, ty = threadIdx.x >> 5;
    const float* src = bz==0 ? a0 : bz==1 ? a1 : bz==2 ? a2 : a3;
    unsigned short* dst = Wt + (size_t)bz*DIM*DIM;
    #pragma unroll
    for (int i=0;i<32;i+=8) tile[ty+i][tx] = f2bf(src[(size_t)(by+ty+i)*DIM + bx+tx]);
    __syncthreads();
    #pragma unroll
    for (int i=0;i<32;i+=8) dst[(size_t)(bx+ty+i)*DIM + by+tx] = tile[tx][ty+i];
  }
}

// ---------------- generic C[M][N] = A1[M][K] * A2[N][K]^T + bias (final O-proj) ----------------
__global__ __launch_bounds__(256) void gemm_bt(
    const unsigned short* __restrict__ A1, const unsigned short* __restrict__ A2,
    const float* __restrict__ bias, unsigned short* __restrict__ C, float* __restrict__ Cf,
    int M, int N, int K, int bias_row)
{
  int lane = threadIdx.x & 63, w = threadIdx.x >> 6;
  int quad = lane >> 4, low = lane & 15;
  int m0 = blockIdx.y*64 + w*16;
  int n0 = blockIdx.x*32;
  f32x4 acc[2];
  acc[0] = (f32x4){0.f,0.f,0.f,0.f};
  acc[1] = (f32x4){0.f,0.f,0.f,0.f};
  #pragma unroll 4
  for (int k0=0; k0<K; k0+=32){
    bf16x8 a = *(const bf16x8*)(A1 + (size_t)(m0+low)*K + k0 + quad*8);
    #pragma unroll
    for (int t=0;t<2;t++){
      bf16x8 b = *(const bf16x8*)(A2 + (size_t)(n0+16*t+low)*K + k0 + quad*8);
      acc[t] = MFMA(a, b, acc[t]);
    }
  }
  #pragma unroll
  for (int t=0;t<2;t++){
    #pragma unroll
    for (int r=0;r<4;r++){
      int row = m0 + quad*4 + r;
      int col = n0 + 16*t + low;
      float v = acc[t][r];
      if (bias) v += bias[bias_row ? row : col];
      if (Cf) Cf[(size_t)row*N + col] = v;
      else    C [(size_t)row*N + col] = f2bf(v);
    }
  }
}

// ---------------- T2 gemm: T2L[l][e][h] = pEF[e]·pEW[l*8+h], per-l 16B rows ----------------
// Layout [8][EPAD][8] bf16: each l's gather window is 525KB -> hot set (l<5) 2.6MB, L2-resident.
__global__ __launch_bounds__(256) void gemm_t2(
    const unsigned short* __restrict__ A1, const unsigned short* __restrict__ A2,
    unsigned short* __restrict__ T2L)
{
  int lane = threadIdx.x & 63, w = threadIdx.x >> 6;
  int quad = lane >> 4, low = lane & 15;
  int m0 = blockIdx.y*64 + w*16;
  int n0 = blockIdx.x*32;
  f32x4 acc[2];
  acc[0] = (f32x4){0.f,0.f,0.f,0.f};
  acc[1] = (f32x4){0.f,0.f,0.f,0.f};
  #pragma unroll
  for (int k0=0; k0<64; k0+=32){
    bf16x8 a = *(const bf16x8*)(A1 + (size_t)(m0+low)*64 + k0 + quad*8);
    #pragma unroll
    for (int t=0;t<2;t++){
      bf16x8 b = *(const bf16x8*)(A2 + (size_t)(n0+16*t+low)*64 + k0 + quad*8);
      acc[t] = MFMA(a, b, acc[t]);
    }
  }
  #pragma unroll
  for (int t=0;t<2;t++){
    #pragma unroll
    for (int r=0;r<4;r++){
      int row = m0 + quad*4 + r;            // edge index
      int col = n0 + 16*t + low;            // l*8+h
      T2L[((size_t)(col>>3)*EPAD + row)*8 + (col&7)] = f2bf(acc[t][r]);
    }
  }
}

// ---------------- co-scheduled bias-gather + fused QKV GEMM ----------------
// blocks 0..511: QKV (MFMA-bound, launched first so they start immediately);
// blocks 512..16895: bias gather (L2-request-bound). Disjoint pipes -> overlap.
// NOTE (R6 lesson): T2L gather loads MUST be normal cached loads — nontemporal
// marks them evict-first in L2 and the gather becomes HBM-latency-bound (331us).
__global__ __launch_bounds__(256) void biasqkv_k(
    const unsigned short* __restrict__ T2L, const float* __restrict__ spb,
    const int* __restrict__ dist, const int* __restrict__ sp, const int* __restrict__ maskp,
    unsigned short* __restrict__ biasB,
    const unsigned short* __restrict__ Xb, const unsigned short* __restrict__ Wt,
    const float* __restrict__ bQ, const float* __restrict__ bK, const float* __restrict__ bV,
    unsigned short* __restrict__ Qb, unsigned short* __restrict__ Kb, unsigned short* __restrict__ Vtb)
{
  __shared__ float sptab[48];
  if (blockIdx.x >= 512){
    // ---------- bias gather ----------
    if (threadIdx.x < 48) sptab[threadIdx.x] = spb[threadIdx.x];
    __syncthreads();
    long pix = (long)(blockIdx.x - 512)*256 + threadIdx.x;   // n*NN + m, covers NN*NN
    int dd = __builtin_nontemporal_load(dist + pix);
    int mk = __builtin_nontemporal_load(maskp + pix);
    int e[5];
    #pragma unroll
    for (int l=0;l<5;l++) e[l] = __builtin_nontemporal_load(sp + pix*5 + l);
    dd = dd < 0 ? 0 : (dd > 5 ? 5 : dd);
    float b[8];
    #pragma unroll
    for (int x=0;x<8;x++) b[x] = sptab[dd*8 + x];
    #pragma unroll
    for (int l=0;l<5;l++){
      int ee = e[l];
      if ((unsigned)ee > (unsigned)NE) ee = NE;
      uint4 tv = *(const uint4*)(T2L + ((size_t)l*EPAD + ee)*8);   // cached: L2-resident window
      b[0] += bf2f(tv.x & 0xffffu); b[1] += bf2f(tv.x >> 16);
      b[2] += bf2f(tv.y & 0xffffu); b[3] += bf2f(tv.y >> 16);
      b[4] += bf2f(tv.z & 0xffffu); b[5] += bf2f(tv.z >> 16);
      b[6] += bf2f(tv.w & 0xffffu); b[7] += bf2f(tv.w >> 16);
    }
    unsigned short o[8];
    #pragma unroll
    for (int x=0;x<8;x++) o[x] = mk ? f2bf(-1e30f) : f2bf(b[x]);
    *(uint4*)(biasB + pix*8) = *(const uint4*)o;
  } else {
    // ---------- fused Q/K/V GEMM: A-fragment loaded once feeds 3 weights ----------
    int bid = blockIdx.x;                  // 0..511 -> (bx 0..15, by 0..31)
    int lane = threadIdx.x & 63, w = threadIdx.x >> 6;
    int quad = lane >> 4, low = lane & 15;
    int m0 = (bid >> 4)*64 + w*16;         // node row
    int n0 = (bid & 15)*32;                // output col
    f32x4 acc[3][2];
    #pragma unroll
    for (int z=0;z<3;z++){ acc[z][0]=(f32x4){0.f,0.f,0.f,0.f}; acc[z][1]=(f32x4){0.f,0.f,0.f,0.f}; }
    #pragma unroll 2
    for (int k0=0; k0<DIM; k0+=32){
      bf16x8 a = *(const bf16x8*)(Xb + (size_t)(m0+low)*DIM + k0 + quad*8);
      #pragma unroll
      for (int z=0;z<3;z++){
        #pragma unroll
        for (int t=0;t<2;t++){
          bf16x8 b = *(const bf16x8*)(Wt + (size_t)z*DIM*DIM + (size_t)(n0+16*t+low)*DIM + k0 + quad*8);
          acc[z][t] = MFMA(a, b, acc[z][t]);
        }
      }
    }
    #pragma unroll
    for (int t=0;t<2;t++){
      #pragma unroll
      for (int r=0;r<4;r++){
        int row = m0 + quad*4 + r;
        int col = n0 + 16*t + low;
        Qb[(size_t)row*DIM + col] = f2bf(acc[0][t][r] + bQ[col]);
        Kb[(size_t)row*DIM + col] = f2bf(acc[1][t][r] + bK[col]);
        Vtb[(size_t)col*NN + row] = f2bf(acc[2][t][r] + bV[col]);
      }
    }
  }
}

// ---------------- fused attention (3-barrier schedule) ----------------
// block = 512 threads = 8 waves, wave h owns head h; QBLK=32 queries/block.
// Softmax over HEADS per (q,m) pair (reference uses axis=-1 on (n,m,h)!).
// Phase B: S=QK^T -> LDS (pure write; barrier hidden under MFMA issue).
// Phase C: bias added from register-prefetched pb + softmax; P written bf16-packed
//          (2 heads/u32) into planes 0..3 of the SAME LDS block (own-slot rewrite, race-free).
// Phase D: PV reads P as 2x uint4 per fragment (no f32->bf16 conversion chain).
__global__ __launch_bounds__(512, 4) void attn_k(
    const unsigned short* __restrict__ Qb, const unsigned short* __restrict__ Kb,
    const unsigned short* __restrict__ Vt, const unsigned short* __restrict__ biasB,
    float* __restrict__ partO)
{
  __shared__ __attribute__((aligned(16))) float sld[NH][QBLK][68];  // 69.6 KB -> 2 blocks/CU
  unsigned int* p2 = (unsigned int*)sld;   // packed-P view: p2[pair*2176 + row*68 + col]
  int tid = threadIdx.x;
  int lane = tid & 63, h = tid >> 6;
  int quad = lane >> 4, low = lane & 15;
  int q0 = blockIdx.x * QBLK;
  int chunk = blockIdx.y;

  bf16x8 aq[2][2];
  #pragma unroll
  for (int sq=0;sq<2;sq++)
    #pragma unroll
    for (int s=0;s<2;s++)
      aq[sq][s] = *(const bf16x8*)(Qb + (size_t)(q0+sq*16+low)*DIM + h*HD + s*32 + quad*8);

  f32x4 accO[2][4];
  #pragma unroll
  for (int sq=0;sq<2;sq++)
    #pragma unroll
    for (int t=0;t<4;t++) accO[sq][t] = (f32x4){0.f,0.f,0.f,0.f};

  // prefetch first key-tile's bias (coalesced: consecutive tid -> consecutive 16B)
  uint4 pb[4];
  #pragma unroll
  for (int it=0; it<4; ++it){
    int p = tid + it*512;
    int qq = p >> 6, mm = p & 63;
    pb[it] = *(const uint4*)(biasB + ((size_t)(q0+qq)*NN + chunk*CHSZ + mm)*8);
  }

  for (int jt=0; jt<NJT; ++jt){
    int m0 = chunk*CHSZ + jt*64;

    // ---- phase B compute: S = Q K^T (registers only) ----
    f32x4 S[2][4];
    #pragma unroll
    for (int sq=0;sq<2;sq++)
      #pragma unroll
      for (int t=0;t<4;t++) S[sq][t] = (f32x4){0.f,0.f,0.f,0.f};
    #pragma unroll
    for (int s=0;s<2;s++){
      #pragma unroll
      for (int t=0;t<4;t++){
        bf16x8 bk = *(const bf16x8*)(Kb + (size_t)(m0+16*t+low)*DIM + h*HD + s*32 + quad*8);
        #pragma unroll
        for (int sq=0;sq<2;sq++)
          S[sq][t] = MFMA(aq[sq][s], bk, S[sq][t]);
      }
    }
    __syncthreads();   // prev iteration's phase-D readers done (wait hides under MFMA)

    // ---- phase B write: raw scores -> LDS (pure write, no bias rmw) ----
    #pragma unroll
    for (int sq=0;sq<2;sq++){
      #pragma unroll
      for (int t=0;t<4;t++){
        #pragma unroll
        for (int r=0;r<4;r++)
          sld[h][sq*16+quad*4+r][low+16*t] = S[sq][t][r]*0.125f;
      }
    }
    __syncthreads();

    // ---- phase C: bias add (from pb regs) + softmax over heads + packed-P write ----
    #pragma unroll
    for (int it=0; it<4; ++it){
      int p = tid + it*512;
      int qq = p >> 6, mm = p & 63;
      uint4 tv = pb[it];
      float s0[8];
      s0[0] = sld[0][qq][mm] + bf2f(tv.x & 0xffffu);
      s0[1] = sld[1][qq][mm] + bf2f(tv.x >> 16);
      s0[2] = sld[2][qq][mm] + bf2f(tv.y & 0xffffu);
      s0[3] = sld[3][qq][mm] + bf2f(tv.y >> 16);
      s0[4] = sld[4][qq][mm] + bf2f(tv.z & 0xffffu);
      s0[5] = sld[5][qq][mm] + bf2f(tv.z >> 16);
      s0[6] = sld[6][qq][mm] + bf2f(tv.w & 0xffffu);
      s0[7] = sld[7][qq][mm] + bf2f(tv.w >> 16);
      float mx = s0[0];
      #pragma unroll
      for (int x=1;x<8;x++) mx = fmaxf(mx, s0[x]);
      float sum = 0.f;
      #pragma unroll
      for (int x=0;x<8;x++){ s0[x] = exp2f((s0[x]-mx)*LOG2E); sum += s0[x]; }
      float inv = (mx < -1e29f) ? 0.f : 1.f/sum;   // fully-masked pair -> zero weights
      #pragma unroll
      for (int pr=0;pr<4;pr++){
        unsigned int u = (unsigned int)f2bf(s0[2*pr]*inv)
                       | ((unsigned int)f2bf(s0[2*pr+1]*inv) << 16);
        p2[pr*2176 + qq*68 + mm] = u;    // own (qq,mm) slot: no cross-thread hazard
      }
    }
    // issue next tile's bias loads (in flight across D + next B)
    if (jt+1 < NJT){
      #pragma unroll
      for (int it=0; it<4; ++it){
        int p = tid + it*512;
        int qq = p >> 6, mm = p & 63;
        pb[it] = *(const uint4*)(biasB + ((size_t)(q0+qq)*NN + m0 + 64 + mm)*8);
      }
    }
    __syncthreads();

    // ---- phase D (wave h): O += P V ----
    bf16x8 ap[2][2];
    #pragma unroll
    for (int sq=0;sq<2;sq++){
      #pragma unroll
      for (int s=0;s<2;s++){
        const uint4* pp = (const uint4*)(p2 + (h>>1)*2176 + (size_t)(sq*16+low)*68 + s*32 + quad*8);
        uint4 w0 = pp[0], w1 = pp[1];
        bf16x8 a;
        if (h & 1){
          a[0]=(short)(w0.x>>16); a[1]=(short)(w0.y>>16); a[2]=(short)(w0.z>>16); a[3]=(short)(w0.w>>16);
          a[4]=(short)(w1.x>>16); a[5]=(short)(w1.y>>16); a[6]=(short)(w1.z>>16); a[7]=(short)(w1.w>>16);
        } else {
          a[0]=(short)(w0.x&0xffffu); a[1]=(short)(w0.y&0xffffu); a[2]=(short)(w0.z&0xffffu); a[3]=(short)(w0.w&0xffffu);
          a[4]=(short)(w1.x&0xffffu); a[5]=(short)(w1.y&0xffffu); a[6]=(short)(w1.z&0xffffu); a[7]=(short)(w1.w&0xffffu);
        }
        ap[sq][s] = a;
      }
    }
    #pragma unroll
    for (int s=0;s<2;s++){
      #pragma unroll
      for (int t=0;t<4;t++){
        bf16x8 bv = *(const bf16x8*)(Vt + (size_t)(h*HD + 16*t + low)*NN + m0 + s*32 + quad*8);
        #pragma unroll
        for (int sq=0;sq<2;sq++)
          accO[sq][t] = MFMA(ap[sq][s], bv, accO[sq][t]);
      }
    }
  }

  // ---- epilogue: per-chunk partial O (plain sum over m; no softmax state) ----
  #pragma unroll
  for (int sq=0;sq<2;sq++){
    #pragma unroll
    for (int t=0;t<4;t++){
      #pragma unroll
      for (int r=0;r<4;r++){
        int q = sq*16 + quad*4 + r;
        partO[(((size_t)chunk*NN + q0 + q)*NH + h)*HD + 16*t + low] = accO[sq][t][r];
      }
    }
  }
}

// ---------------- sum the CHUNKS partial O's, emit bf16 ----------------
__global__ __launch_bounds__(512) void merge_k(const float* __restrict__ partO,
                                               unsigned short* __restrict__ Obf)
{
  size_t idx = (size_t)blockIdx.x*512 + threadIdx.x;   // q*512 + h*64 + d
  float s = 0.f;
  #pragma unroll
  for (int c=0;c<CHUNKS;c++) s += partO[(size_t)c*NN*DIM + idx];
  Obf[idx] = f2bf(s);
}

extern "C" void kernel_launch(void* const* d_in, const int* in_sizes, int n_in,
                              void* d_out, int out_size, void* d_ws, size_t ws_size,
                              hipStream_t stream)
{
  const float* X    = (const float*)d_in[0];
  const int*  dist  = (const int*)d_in[3];
  const int*  sp    = (const int*)d_in[4];
  const float* ef   = (const float*)d_in[5];
  const int*  maskp = (const int*)d_in[6];
  const float* WQ   = (const float*)d_in[7];
  const float* bQ   = (const float*)d_in[8];
  const float* WK   = (const float*)d_in[9];
  const float* bK   = (const float*)d_in[10];
  const float* WV   = (const float*)d_in[11];
  const float* bV   = (const float*)d_in[12];
  const float* WO   = (const float*)d_in[13];
  const float* bO   = (const float*)d_in[14];
  const float* spb  = (const float*)d_in[15];
  const float* ew   = (const float*)d_in[16];

  char* ws = (char*)d_ws;
  unsigned short* Wt   = (unsigned short*)(ws + 0);            // 4 x 512x512 bf16 (Q,K,V,O transposed)
  unsigned short* Xb   = (unsigned short*)(ws + 2097152);      // 2048x512 bf16 node_feat
  unsigned short* Qb   = (unsigned short*)(ws + 4194304);      // 2048x512 bf16
  unsigned short* Kb   = (unsigned short*)(ws + 6291456);      // 2048x512 bf16
  unsigned short* Vtb  = (unsigned short*)(ws + 8388608);      // 512x2048 bf16 (transposed V)
  unsigned short* pEF  = (unsigned short*)(ws + 10485760);     // EPAD x 64 bf16
  unsigned short* pEW  = (unsigned short*)(ws + 14688256);     // 64 x 64 bf16
  unsigned short* T2L  = (unsigned short*)(ws + 14696448);     // [8][EPAD][8] bf16 per-l rows (4.2MB)
  unsigned short* Obf  = (unsigned short*)(ws + 18898944);     // 2048x512 bf16
  unsigned short* biasB= (unsigned short*)(ws + 20996096);     // NN x NN x 8 bf16 (67 MB)
  float*          pO   = (float*)(ws + 88104960);              // CHUNKS x 2048x512 f32 (33.5 MB; ws ~122 MB)

  prep_k<<<dim3(2564), dim3(256), 0, stream>>>(X, ef, ew, Xb, pEF, pEW, WQ, WK, WV, WO, Wt);
  gemm_t2<<<dim3(2,513), dim3(256), 0, stream>>>(pEF, pEW, T2L);
  biasqkv_k<<<dim3(512 + NN*NN/256), dim3(256), 0, stream>>>(
      T2L, spb, dist, sp, maskp, biasB, Xb, Wt, bQ, bK, bV, Qb, Kb, Vtb);
  attn_k<<<dim3(NN/QBLK, CHUNKS), dim3(512), 0, stream>>>(Qb, Kb, Vtb, biasB, pO);
  merge_k<<<dim3(2048), dim3(512), 0, stream>>>(pO, Obf);
  gemm_bt<<<dim3(16,32), dim3(256), 0, stream>>>(Obf, Wt + 786432, bO, (unsigned short*)nullptr, (float*)d_out, NN, DIM, DIM, 0);
}